// Round 10
// baseline (251.629 us; speedup 1.0000x reference)
//
#include <hip/hip_runtime.h>
#include <hip/hip_bf16.h>
#include <math.h>

#define BB 128
#define TT 64
#define DD 64
#define HH 128
#define NHH 4
#define K3H 384        // 3*H

typedef __attribute__((ext_vector_type(8))) short short8_t;   // 8 bf16
typedef __attribute__((ext_vector_type(4))) float float4_t;

#define LOG2E 1.4426950408889634f

__device__ __forceinline__ unsigned short f2bf(float f) {
    unsigned int u = __float_as_uint(f);
    u += 0x7fffu + ((u >> 16) & 1u);      // RNE
    return (unsigned short)(u >> 16);
}

__device__ __forceinline__ unsigned pack_bf2(float lo, float hi) {
    return (unsigned)f2bf(lo) | ((unsigned)f2bf(hi) << 16);
}

__device__ __forceinline__ unsigned pack_bf2_hw(float lo, float hi) {
    __hip_bfloat162 p = __float22bfloat162_rn(make_float2(lo, hi));
    unsigned u;
    __builtin_memcpy(&u, &p, 4);
    return u;
}

__device__ __forceinline__ float bf2f(unsigned short s) {
    return __uint_as_float((unsigned)s << 16);
}

// ---------------- per-feature GRU via bf16 MFMA ---------------------------
// bias folded into MFMA acc init; HW packed bf16 writeback.
__global__ __launch_bounds__(512, 4) void gru_mfma_kernel(
    const float* __restrict__ x, const int* __restrict__ mask,
    const float* __restrict__ Wih, const float* __restrict__ Whh,
    const float* __restrict__ bih, const float* __restrict__ bhh,
    float* __restrict__ emb)
{
    const int d  = blockIdx.x;
    const int b0 = blockIdx.y * 16;
    const int tid = threadIdx.x;
    const int w = tid >> 6;
    const int l = tid & 63;
    const int m = l & 15;
    const int q = l >> 4;

    __shared__ __align__(16) unsigned short hbuf[2][16][136];
    __shared__ float xs_t[TT][16];
    __shared__ int tstar_s[16];

    for (int idx = tid; idx < 16 * TT; idx += 512) {
        int t = idx >> 4, row = idx & 15;
        xs_t[t][row] = x[((size_t)(b0 + row) * TT + t) * DD + d];
    }
    if (tid < 16) {
        int b = b0 + tid, len = 0;
        for (int t = 0; t < TT; ++t) len += mask[b * TT + t];
        int ts = len - 1;
        if (ts < 0) ts = 0;
        if (ts > TT - 1) ts = TT - 1;
        tstar_s[tid] = ts;
    }
    for (int idx = tid; idx < 16 * 136; idx += 512)
        ((unsigned short*)hbuf)[idx] = 0;

    short8_t Wf[3][4];
#pragma unroll
    for (int g = 0; g < 3; ++g) {
        float sc = (g == 2) ? (2.f * LOG2E) : (-LOG2E);
        int kcol = g * HH + 16 * w + m;
        const float* wrow = Whh + ((size_t)d * K3H + kcol) * HH;
#pragma unroll
        for (int kc = 0; kc < 4; ++kc) {
            int j0 = kc * 32 + q * 8;
            float4 w0 = *(const float4*)(wrow + j0);
            float4 w1 = *(const float4*)(wrow + j0 + 4);
            short8_t f;
            f[0] = (short)f2bf(w0.x * sc); f[1] = (short)f2bf(w0.y * sc);
            f[2] = (short)f2bf(w0.z * sc); f[3] = (short)f2bf(w0.w * sc);
            f[4] = (short)f2bf(w1.x * sc); f[5] = (short)f2bf(w1.y * sc);
            f[6] = (short)f2bf(w1.z * sc); f[7] = (short)f2bf(w1.w * sc);
            Wf[g][kc] = f;
        }
    }

    const int hcol0 = 16 * w + q * 4;
    float4 wr4 = *(const float4*)&Wih[d * K3H + hcol0];
    float4 wz4 = *(const float4*)&Wih[d * K3H + HH + hcol0];
    float4 wn4 = *(const float4*)&Wih[d * K3H + 2 * HH + hcol0];
    float4 br4 = *(const float4*)&bih[d * K3H + hcol0];
    float4 bz4 = *(const float4*)&bih[d * K3H + HH + hcol0];
    float4 bni4 = *(const float4*)&bih[d * K3H + 2 * HH + hcol0];
    float4 bhr4 = *(const float4*)&bhh[d * K3H + hcol0];
    float4 bhz4 = *(const float4*)&bhh[d * K3H + HH + hcol0];
    float4 bnh4 = *(const float4*)&bhh[d * K3H + 2 * HH + hcol0];
    float brs[4], bzs[4], bnis[4], bnhs[4], wrs[4], wzs[4], wns[4];
#pragma unroll
    for (int r = 0; r < 4; ++r) {
        wrs[r] = -LOG2E * ((const float*)&wr4)[r];
        wzs[r] = -LOG2E * ((const float*)&wz4)[r];
        wns[r] = 2.f * LOG2E * ((const float*)&wn4)[r];
        brs[r] = -LOG2E * (((const float*)&br4)[r] + ((const float*)&bhr4)[r]);
        bzs[r] = -LOG2E * (((const float*)&bz4)[r] + ((const float*)&bhz4)[r]);
        bnis[r] = 2.f * LOG2E * ((const float*)&bni4)[r];
        bnhs[r] = 2.f * LOG2E * ((const float*)&bnh4)[r];
    }

    float hprev[4];
#pragma unroll
    for (int i = 0; i < 4; ++i) hprev[i] = 0.f;

    __syncthreads();
    const int tstar_m = tstar_s[m];
    float* embp = emb + (((size_t)(b0 + m)) * DD + d) * HH + hcol0;

    for (int t = 0; t < TT; ++t) {
        const unsigned short* hb = &hbuf[t & 1][0][0];
        unsigned short* hbn = &hbuf[(t & 1) ^ 1][0][0];

        short8_t hf[4];
#pragma unroll
        for (int kc = 0; kc < 4; ++kc)
            hf[kc] = *(const short8_t*)(hb + m * 136 + kc * 32 + q * 8);
        float xv = xs_t[t][m];

        // biases pre-loaded into accumulators
        float4_t ar = {brs[0], brs[1], brs[2], brs[3]};
        float4_t az = {bzs[0], bzs[1], bzs[2], bzs[3]};
        float4_t an = {bnhs[0], bnhs[1], bnhs[2], bnhs[3]};
#pragma unroll
        for (int kc = 0; kc < 4; ++kc) {
            ar = __builtin_amdgcn_mfma_f32_16x16x32_bf16(Wf[0][kc], hf[kc], ar, 0, 0, 0);
            az = __builtin_amdgcn_mfma_f32_16x16x32_bf16(Wf[1][kc], hf[kc], az, 0, 0, 0);
            an = __builtin_amdgcn_mfma_f32_16x16x32_bf16(Wf[2][kc], hf[kc], an, 0, 0, 0);
        }

        float hn4[4];
#pragma unroll
        for (int reg = 0; reg < 4; ++reg) {
            float grs = fmaf(xv, wrs[reg], ar[reg]);
            float gzs = fmaf(xv, wzs[reg], az[reg]);
            float rg = __builtin_amdgcn_rcpf(1.f + __builtin_amdgcn_exp2f(grs));
            float zg = __builtin_amdgcn_rcpf(1.f + __builtin_amdgcn_exp2f(gzs));
            float gns = fmaf(rg, an[reg], fmaf(xv, wns[reg], bnis[reg]));
            float tn = fmaf(-2.f, __builtin_amdgcn_rcpf(__builtin_amdgcn_exp2f(gns) + 1.f), 1.f);
            float hn = fmaf(zg, hprev[reg] - tn, tn);
            hprev[reg] = hn;
            hn4[reg] = hn;
        }
        uint2 uu;
        uu.x = pack_bf2_hw(hn4[0], hn4[1]);
        uu.y = pack_bf2_hw(hn4[2], hn4[3]);
        *(uint2*)(hbn + m * 136 + hcol0) = uu;
        if (t == tstar_m) {
            float4 hv; hv.x = hn4[0]; hv.y = hn4[1]; hv.z = hn4[2]; hv.w = hn4[3];
            *(float4*)embp = hv;
        }
        __syncthreads();
    }
}

// ============ fused tail v3: 2 blocks per batch element ===================
// grid 256 = (b, half); block half owns Q/token rows [half*32, half*32+32).
// K, V computed redundantly (full 64 rows). 512 threads, 8 waves.
//   A-frag: lane = S[row0 + mt*16 + (l&15)][kc*32 + q*8 + j]
//   B-frag (regs): lane = W[kc*32+q*8+j][16w + (l&15)]
//   C: row = row0 + mt*16 + q*4 + reg, col = 16w + (l&15)

__device__ __forceinline__ void load_wfrag(const float* __restrict__ Wp, int N,
                                           int col, float scale, int q,
                                           short8_t fr[4])
{
#pragma unroll
    for (int kc = 0; kc < 4; ++kc) {
        const float* p = Wp + (size_t)(kc * 32 + q * 8) * N + col;
        short8_t f;
#pragma unroll
        for (int j = 0; j < 8; ++j)
            f[j] = (short)f2bf(p[(size_t)j * N] * scale);
        fr[kc] = f;
    }
}

__global__ __launch_bounds__(512) void tail_kernel(
    const float* __restrict__ emb,
    const float* __restrict__ Wq, const float* __restrict__ bq,
    const float* __restrict__ Wk, const float* __restrict__ bk,
    const float* __restrict__ Wv, const float* __restrict__ bv,
    const float* __restrict__ Wo, const float* __restrict__ bo,
    const float* __restrict__ W1, const float* __restrict__ b1,
    const float* __restrict__ W2, const float* __restrict__ b2,
    const float* __restrict__ g1, const float* __restrict__ be1,
    const float* __restrict__ g2, const float* __restrict__ be2,
    const float* __restrict__ Fq, const float* __restrict__ fbq,
    const float* __restrict__ Fk, const float* __restrict__ fbk,
    const float* __restrict__ Fv, const float* __restrict__ fbv,
    float* __restrict__ fkb, float* __restrict__ fvb, float* __restrict__ fqb)
{
    const int b = blockIdx.x >> 1;
    const int half = blockIdx.x & 1;
    const int r0 = half * 32;
    const int tid = threadIdx.x;
    const int w = tid >> 6, l = tid & 63, m16 = l & 15, q = l >> 4;
    const int col = w * 16 + m16;

    __shared__ __align__(16) unsigned short E[64][136];   // emb -> o/h1/h2 (local rows)
    __shared__ __align__(16) unsigned short Qs[64][136];  // Q(local) -> P(all heads) -> a1lo
    __shared__ __align__(16) unsigned short Ks[64][136];  // K(full) -> a1hi
    __shared__ __align__(16) unsigned short Vt[128][72];  // V transposed (full)
    __shared__ float sc4[4][32][66];                      // scores: 4 heads x 32 local rows
    __shared__ float lnp[32][8], lnp2[32][8];
    __shared__ float mean_s[32], rs_s[32];

    const float* embB = emb + (size_t)b * 64 * 128;
    const float SS = 0.17677669529663687f;   // 1/sqrt(32)

    // ---- prefetch QKV weight frags (covers emb staging) ----
    short8_t WqF[4], WkF[4], WvF[4];
    load_wfrag(Wq, 128, col, SS, q, WqF);
    load_wfrag(Wk, 128, col, 1.f, q, WkF);
    load_wfrag(Wv, 128, col, 1.f, q, WvF);
    float bqv = bq[col] * SS, bkv = bk[col], bvv = bv[col];

    // ---- stage emb fp32 -> bf16 (full 64 rows) ----
    for (int it = tid; it < 2048; it += 512) {
        int r = it >> 5, c4 = (it & 31) << 2;
        float4 a = *(const float4*)&embB[r * 128 + c4];
        uint2 p; p.x = pack_bf2(a.x, a.y); p.y = pack_bf2(a.z, a.w);
        *(uint2*)&E[r][c4] = p;
    }
    __syncthreads();                                   // B0

    short8_t Af4[4][4];
#pragma unroll
    for (int mt = 0; mt < 4; ++mt)
#pragma unroll
        for (int kc = 0; kc < 4; ++kc)
            Af4[mt][kc] = *(const short8_t*)&E[mt * 16 + m16][kc * 32 + q * 8];

    // ---- K full, V full (transposed), Q local ----
    {
        float4_t a4[4];
#pragma unroll
        for (int mt = 0; mt < 4; ++mt) {
            float4_t a = {0.f, 0.f, 0.f, 0.f};
#pragma unroll
            for (int kc = 0; kc < 4; ++kc)
                a = __builtin_amdgcn_mfma_f32_16x16x32_bf16(Af4[mt][kc], WkF[kc], a, 0, 0, 0);
            a4[mt] = a;
        }
#pragma unroll
        for (int mt = 0; mt < 4; ++mt)
#pragma unroll
            for (int reg = 0; reg < 4; ++reg)
                Ks[mt * 16 + q * 4 + reg][col] = f2bf(a4[mt][reg] + bkv);
#pragma unroll
        for (int mt = 0; mt < 4; ++mt) {
            float4_t a = {0.f, 0.f, 0.f, 0.f};
#pragma unroll
            for (int kc = 0; kc < 4; ++kc)
                a = __builtin_amdgcn_mfma_f32_16x16x32_bf16(Af4[mt][kc], WvF[kc], a, 0, 0, 0);
            uint2 pk;
            pk.x = pack_bf2(a[0] + bvv, a[1] + bvv);
            pk.y = pack_bf2(a[2] + bvv, a[3] + bvv);
            *(uint2*)&Vt[col][mt * 16 + q * 4] = pk;
        }
#pragma unroll
        for (int mt = 0; mt < 2; ++mt) {
            float4_t a = {0.f, 0.f, 0.f, 0.f};
#pragma unroll
            for (int kc = 0; kc < 4; ++kc)
                a = __builtin_amdgcn_mfma_f32_16x16x32_bf16(Af4[half * 2 + mt][kc], WqF[kc], a, 0, 0, 0);
#pragma unroll
            for (int reg = 0; reg < 4; ++reg)
                Qs[r0 + mt * 16 + q * 4 + reg][col] = f2bf(a[reg] + bqv);
        }
    }
    __syncthreads();                                   // B1

    // ---- prefetch Wo, W1 frags (covers attention) ----
    short8_t WoF[4], W1aF[4], W1bF[4];
    load_wfrag(Wo, 128, col, 1.f, q, WoF);
    load_wfrag(W1, 256, col, 1.f, q, W1aF);
    load_wfrag(W1, 256, 128 + col, 1.f, q, W1bF);
    float bov = bo[col], b1a = b1[col], b1b = b1[128 + col];
    float g1v = g1[col], be1v = be1[col];

    // ---- scores: 4 heads x (32 local q-rows x 64 k-cols) ----
    {
        int hd = w >> 1, ntb = (w & 1) * 2;
#pragma unroll
        for (int mt = 0; mt < 2; ++mt) {
            short8_t Aq = *(const short8_t*)&Qs[r0 + mt * 16 + m16][hd * 32 + q * 8];
#pragma unroll
            for (int nn = 0; nn < 2; ++nn) {
                int nt = ntb + nn;
                short8_t Bk = *(const short8_t*)&Ks[nt * 16 + m16][hd * 32 + q * 8];
                float4_t a = {0.f, 0.f, 0.f, 0.f};
                a = __builtin_amdgcn_mfma_f32_16x16x32_bf16(Aq, Bk, a, 0, 0, 0);
#pragma unroll
                for (int reg = 0; reg < 4; ++reg)
                    sc4[hd][mt * 16 + q * 4 + reg][nt * 16 + m16] = a[reg];
            }
        }
    }
    __syncthreads();                                   // B2

    // ---- softmax (4 thr/row); P bf16 (1/sum folded) -> Qs all rows ----
    {
        int pr = tid >> 2, sub = tid & 3;   // pr 0..127: hd x 32 rows
        int hd2 = pr >> 5, row = pr & 31;
        float v[16]; float mx = -1e30f;
#pragma unroll
        for (int c = 0; c < 16; ++c) { v[c] = sc4[hd2][row][sub * 16 + c]; mx = fmaxf(mx, v[c]); }
        mx = fmaxf(mx, __shfl_xor(mx, 1));
        mx = fmaxf(mx, __shfl_xor(mx, 2));
        float sum = 0.f;
#pragma unroll
        for (int c = 0; c < 16; ++c) { v[c] = __expf(v[c] - mx); sum += v[c]; }
        sum += __shfl_xor(sum, 1); sum += __shfl_xor(sum, 2);
        float inv = __builtin_amdgcn_rcpf(sum);
        int prow = (hd2 >> 1) * 32 + row, pc = (hd2 & 1) * 64 + sub * 16;
#pragma unroll
        for (int c = 0; c < 8; ++c)
            *(unsigned*)&Qs[prow][pc + 2 * c] = pack_bf2(v[2 * c] * inv, v[2 * c + 1] * inv);
    }
    __syncthreads();                                   // B3

    // ---- PV via MFMA (K=64): local rows x all 128 V-cols -> E ----
    {
        int hd = w >> 1, ntv = w & 1;
        int vrow = hd * 32 + ntv * 16 + m16;
        short8_t B0f = *(const short8_t*)&Vt[vrow][q * 8];
        short8_t B1f = *(const short8_t*)&Vt[vrow][32 + q * 8];
        int prow0 = (hd >> 1) * 32, pc = (hd & 1) * 64;
#pragma unroll
        for (int mt = 0; mt < 2; ++mt) {
            short8_t A0 = *(const short8_t*)&Qs[prow0 + mt * 16 + m16][pc + q * 8];
            short8_t A1 = *(const short8_t*)&Qs[prow0 + mt * 16 + m16][pc + 32 + q * 8];
            float4_t a = {0.f, 0.f, 0.f, 0.f};
            a = __builtin_amdgcn_mfma_f32_16x16x32_bf16(A0, B0f, a, 0, 0, 0);
            a = __builtin_amdgcn_mfma_f32_16x16x32_bf16(A1, B1f, a, 0, 0, 0);
#pragma unroll
            for (int reg = 0; reg < 4; ++reg)
                E[r0 + mt * 16 + q * 4 + reg][vrow] = f2bf(a[reg]);
        }
    }
    __syncthreads();                                   // B4

    // ---- prefetch W2, Fk, Fv frags (covers Wo/LN1/FFN1) ----
    short8_t W2aF[4], W2bF[4], FkF[4], FvF[4];
    load_wfrag(W2, 128, col, 1.f, q, W2aF);
    load_wfrag(W2 + (size_t)128 * 128, 128, col, 1.f, q, W2bF);
    load_wfrag(Fk, 128, col, 1.f, q, FkF);
    load_wfrag(Fv, 128, col, 1.f, q, FvF);
    float b2v = b2[col], fbkv = fbk[col], fbvv = fbv[col];
    float g2v = g2[col], be2v = be2[col];

    // ---- Wo + residual(emb) + LN1 -> E local (h1 bf16), h1 in regs ----
    short8_t Af2[2][4];
#pragma unroll
    for (int mt = 0; mt < 2; ++mt)
#pragma unroll
        for (int kc = 0; kc < 4; ++kc)
            Af2[mt][kc] = *(const short8_t*)&E[r0 + mt * 16 + m16][kc * 32 + q * 8];
    float h1v[2][4];
#pragma unroll
    for (int mt = 0; mt < 2; ++mt) {
        float4_t a = {0.f, 0.f, 0.f, 0.f};
#pragma unroll
        for (int kc = 0; kc < 4; ++kc)
            a = __builtin_amdgcn_mfma_f32_16x16x32_bf16(Af2[mt][kc], WoF[kc], a, 0, 0, 0);
#pragma unroll
        for (int reg = 0; reg < 4; ++reg) {
            int row = r0 + mt * 16 + q * 4 + reg;
            h1v[mt][reg] = a[reg] + bov + embB[(size_t)row * 128 + col];
        }
    }
#pragma unroll
    for (int mt = 0; mt < 2; ++mt)
#pragma unroll
        for (int reg = 0; reg < 4; ++reg) {
            float s = h1v[mt][reg], s2 = s * s;
            s += __shfl_xor(s, 1); s += __shfl_xor(s, 2); s += __shfl_xor(s, 4); s += __shfl_xor(s, 8);
            s2 += __shfl_xor(s2, 1); s2 += __shfl_xor(s2, 2); s2 += __shfl_xor(s2, 4); s2 += __shfl_xor(s2, 8);
            if (m16 == 0) { int lr = mt * 16 + q * 4 + reg; lnp[lr][w] = s; lnp2[lr][w] = s2; }
        }
    __syncthreads();                                   // B5
    if (tid < 32) {
        float s = 0.f, s2 = 0.f;
#pragma unroll
        for (int k = 0; k < 8; ++k) { s += lnp[tid][k]; s2 += lnp2[tid][k]; }
        float mn = s * (1.f / 128.f);
        mean_s[tid] = mn;
        rs_s[tid] = rsqrtf(s2 * (1.f / 128.f) - mn * mn + 1e-5f);
    }
    __syncthreads();                                   // B6
#pragma unroll
    for (int mt = 0; mt < 2; ++mt)
#pragma unroll
        for (int reg = 0; reg < 4; ++reg) {
            int lr = mt * 16 + q * 4 + reg;
            float hv = (h1v[mt][reg] - mean_s[lr]) * rs_s[lr] * g1v + be1v;
            h1v[mt][reg] = hv;
            E[r0 + lr][col] = f2bf(hv);
        }
    __syncthreads();                                   // B7

    // ---- FFN1: a1 = relu(h1 @ W1 + b1) -> Qs (lo), Ks (hi), local rows ----
#pragma unroll
    for (int mt = 0; mt < 2; ++mt)
#pragma unroll
        for (int kc = 0; kc < 4; ++kc)
            Af2[mt][kc] = *(const short8_t*)&E[r0 + mt * 16 + m16][kc * 32 + q * 8];
#pragma unroll
    for (int mt = 0; mt < 2; ++mt) {
        float4_t a = {0.f, 0.f, 0.f, 0.f}, c2 = {0.f, 0.f, 0.f, 0.f};
#pragma unroll
        for (int kc = 0; kc < 4; ++kc) {
            a  = __builtin_amdgcn_mfma_f32_16x16x32_bf16(Af2[mt][kc], W1aF[kc], a, 0, 0, 0);
            c2 = __builtin_amdgcn_mfma_f32_16x16x32_bf16(Af2[mt][kc], W1bF[kc], c2, 0, 0, 0);
        }
#pragma unroll
        for (int reg = 0; reg < 4; ++reg) {
            int row = r0 + mt * 16 + q * 4 + reg;
            Qs[row][col] = f2bf(fmaxf(a[reg] + b1a, 0.f));
            Ks[row][col] = f2bf(fmaxf(c2[reg] + b1b, 0.f));
        }
    }
    __syncthreads();                                   // B8

    // ---- FFN2 (K=256) + residual(h1 regs) + LN2 -> E local (h2) ----
#pragma unroll
    for (int mt = 0; mt < 2; ++mt) {
        float4_t a = {0.f, 0.f, 0.f, 0.f};
#pragma unroll
        for (int kc = 0; kc < 4; ++kc) {
            short8_t AQ = *(const short8_t*)&Qs[r0 + mt * 16 + m16][kc * 32 + q * 8];
            a = __builtin_amdgcn_mfma_f32_16x16x32_bf16(AQ, W2aF[kc], a, 0, 0, 0);
        }
#pragma unroll
        for (int kc = 0; kc < 4; ++kc) {
            short8_t AK = *(const short8_t*)&Ks[r0 + mt * 16 + m16][kc * 32 + q * 8];
            a = __builtin_amdgcn_mfma_f32_16x16x32_bf16(AK, W2bF[kc], a, 0, 0, 0);
        }
#pragma unroll
        for (int reg = 0; reg < 4; ++reg)
            h1v[mt][reg] = a[reg] + b2v + h1v[mt][reg];
    }
#pragma unroll
    for (int mt = 0; mt < 2; ++mt)
#pragma unroll
        for (int reg = 0; reg < 4; ++reg) {
            float s = h1v[mt][reg], s2 = s * s;
            s += __shfl_xor(s, 1); s += __shfl_xor(s, 2); s += __shfl_xor(s, 4); s += __shfl_xor(s, 8);
            s2 += __shfl_xor(s2, 1); s2 += __shfl_xor(s2, 2); s2 += __shfl_xor(s2, 4); s2 += __shfl_xor(s2, 8);
            if (m16 == 0) { int lr = mt * 16 + q * 4 + reg; lnp[lr][w] = s; lnp2[lr][w] = s2; }
        }
    __syncthreads();                                   // B9
    if (tid < 32) {
        float s = 0.f, s2 = 0.f;
#pragma unroll
        for (int k = 0; k < 8; ++k) { s += lnp[tid][k]; s2 += lnp2[tid][k]; }
        float mn = s * (1.f / 128.f);
        mean_s[tid] = mn;
        rs_s[tid] = rsqrtf(s2 * (1.f / 128.f) - mn * mn + 1e-5f);
    }
    __syncthreads();                                   // B10
#pragma unroll
    for (int mt = 0; mt < 2; ++mt)
#pragma unroll
        for (int reg = 0; reg < 4; ++reg) {
            int lr = mt * 16 + q * 4 + reg;
            float hv = (h1v[mt][reg] - mean_s[lr]) * rs_s[lr] * g2v + be2v;
            E[r0 + lr][col] = f2bf(hv);   // h2
        }
    __syncthreads();                                   // B11

    // ---- fk, fv -> global (fp32, local rows); fq (half 1 only) ----
#pragma unroll
    for (int mt = 0; mt < 2; ++mt)
#pragma unroll
        for (int kc = 0; kc < 4; ++kc)
            Af2[mt][kc] = *(const short8_t*)&E[r0 + mt * 16 + m16][kc * 32 + q * 8];
#pragma unroll
    for (int mt = 0; mt < 2; ++mt) {
        float4_t a = {0.f, 0.f, 0.f, 0.f}, c2 = {0.f, 0.f, 0.f, 0.f};
#pragma unroll
        for (int kc = 0; kc < 4; ++kc) {
            a  = __builtin_amdgcn_mfma_f32_16x16x32_bf16(Af2[mt][kc], FkF[kc], a, 0, 0, 0);
            c2 = __builtin_amdgcn_mfma_f32_16x16x32_bf16(Af2[mt][kc], FvF[kc], c2, 0, 0, 0);
        }
#pragma unroll
        for (int reg = 0; reg < 4; ++reg) {
            int row = r0 + mt * 16 + q * 4 + reg;
            fkb[((size_t)b * DD + row) * HH + col] = a[reg] + fbkv;
            fvb[((size_t)b * DD + row) * HH + col] = c2[reg] + fbvv;
        }
    }
    if (half == 1) {   // fq = h2[row 63] @ Fq + fbq, 4 threads per col
        int co = tid >> 2, sub = tid & 3;
        float acc = 0.f;
#pragma unroll 8
        for (int mm2 = sub * 32; mm2 < sub * 32 + 32; ++mm2)
            acc = fmaf(bf2f(E[63][mm2]), Fq[(size_t)mm2 * 128 + co], acc);
        acc += __shfl_xor(acc, 1);
        acc += __shfl_xor(acc, 2);
        if (sub == 0) fqb[(size_t)b * 128 + co] = acc + fbq[co];
    }
}

// ---------------- final: e=tanh(fq+fk)@Fout, softmax, out=a@fv ------------
__global__ __launch_bounds__(256) void final_reduce_kernel(
    const float* __restrict__ fqb, const float* __restrict__ fkb,
    const float* __restrict__ fvb, const float* __restrict__ Fout,
    const float* __restrict__ fbout, float* __restrict__ out)
{
    int b = blockIdx.x;
    int tid = threadIdx.x;
    __shared__ float fq_s[HH], fo_s[HH], e_s[DD];
    __shared__ float red_s[256];
    if (tid < HH) {
        fq_s[tid] = fqb[(size_t)b * HH + tid];
        fo_s[tid] = Fout[tid];
    }
    __syncthreads();
    int dd = tid >> 2, sub = tid & 3;
    const float* fkrow = fkb + ((size_t)b * DD + dd) * HH + sub * 32;
    float p = 0.f;
#pragma unroll 8
    for (int mm = 0; mm < 32; ++mm)
        p = fmaf(tanhf(fq_s[sub * 32 + mm] + fkrow[mm]), fo_s[sub * 32 + mm], p);
    p += __shfl_xor(p, 1);
    p += __shfl_xor(p, 2);
    if (sub == 0) e_s[dd] = p + fbout[0];
    __syncthreads();
    if (tid < 64) {
        float e = e_s[tid], mx = e;
        for (int o = 32; o; o >>= 1) mx = fmaxf(mx, __shfl_xor(mx, o));
        float pe = __expf(e - mx);
        float s = pe;
        for (int o = 32; o; o >>= 1) s += __shfl_xor(s, o);
        e_s[tid] = pe / s;
    }
    __syncthreads();
    int col = tid & 127, rg = tid >> 7;
    float acc = 0.f;
    for (int d2 = rg * 32; d2 < rg * 32 + 32; ++d2)
        acc = fmaf(e_s[d2], fvb[((size_t)b * DD + d2) * HH + col], acc);
    red_s[tid] = acc;
    __syncthreads();
    if (rg == 0)
        out[(size_t)b * HH + col] = red_s[col] + red_s[col + 128];
}

// ---------------- launch ---------------------------------------------------
extern "C" void kernel_launch(void* const* d_in, const int* in_sizes, int n_in,
                              void* d_out, int out_size, void* d_ws, size_t ws_size,
                              hipStream_t stream)
{
    const float* x    = (const float*)d_in[0];
    const int*   mask = (const int*)d_in[1];
    const float* Wih  = (const float*)d_in[2];
    const float* Whh  = (const float*)d_in[3];
    const float* bih  = (const float*)d_in[4];
    const float* bhh  = (const float*)d_in[5];
    const float* Wq = (const float*)d_in[6];   const float* bq = (const float*)d_in[7];
    const float* Wk = (const float*)d_in[8];   const float* bk = (const float*)d_in[9];
    const float* Wv = (const float*)d_in[10];  const float* bv = (const float*)d_in[11];
    const float* Wo = (const float*)d_in[12];  const float* bo = (const float*)d_in[13];
    const float* W1 = (const float*)d_in[14];  const float* b1 = (const float*)d_in[15];
    const float* W2 = (const float*)d_in[16];  const float* b2 = (const float*)d_in[17];
    const float* g1 = (const float*)d_in[18];  const float* be1 = (const float*)d_in[19];
    const float* g2 = (const float*)d_in[20];  const float* be2 = (const float*)d_in[21];
    const float* Fq = (const float*)d_in[22];  const float* fbq = (const float*)d_in[23];
    const float* Fk = (const float*)d_in[24];  const float* fbk = (const float*)d_in[25];
    const float* Fv = (const float*)d_in[26];  const float* fbv = (const float*)d_in[27];
    const float* Fout = (const float*)d_in[28]; const float* fbout = (const float*)d_in[29];
    float* out = (float*)d_out;
    float* ws  = (float*)d_ws;

    float* emb = ws;                  // 1048576 floats
    float* fkb = ws + 1048576;        // 1048576
    float* fvb = ws + 2097152;        // 1048576
    float* fqb = ws + 3145728;        // 16384

    gru_mfma_kernel<<<dim3(DD, BB / 16), 512, 0, stream>>>(x, mask, Wih, Whh, bih, bhh, emb);
    tail_kernel<<<BB * 2, 512, 0, stream>>>(
        emb, Wq, bq, Wk, bk, Wv, bv, Wo, bo, W1, b1, W2, b2,
        g1, be1, g2, be2, Fq, fbq, Fk, fbk, Fv, fbv, fkb, fvb, fqb);
    final_reduce_kernel<<<BB, 256, 0, stream>>>(fqb, fkb, fvb, Fout, fbout, out);
}

// Round 11
// 247.647 us; speedup vs baseline: 1.0161x; 1.0161x over previous
//
#include <hip/hip_runtime.h>
#include <hip/hip_bf16.h>
#include <math.h>

#define BB 128
#define TT 64
#define DD 64
#define HH 128
#define NHH 4
#define K3H 384        // 3*H

typedef __attribute__((ext_vector_type(8))) short short8_t;   // 8 bf16
typedef __attribute__((ext_vector_type(4))) float float4_t;

#define LOG2E 1.4426950408889634f

__device__ __forceinline__ unsigned short f2bf(float f) {
    unsigned int u = __float_as_uint(f);
    u += 0x7fffu + ((u >> 16) & 1u);      // RNE
    return (unsigned short)(u >> 16);
}

__device__ __forceinline__ unsigned pack_bf2(float lo, float hi) {
    return (unsigned)f2bf(lo) | ((unsigned)f2bf(hi) << 16);
}

__device__ __forceinline__ unsigned pack_bf2_hw(float lo, float hi) {
    __hip_bfloat162 p = __float22bfloat162_rn(make_float2(lo, hi));
    unsigned u;
    __builtin_memcpy(&u, &p, 4);
    return u;
}

__device__ __forceinline__ float bf2f(unsigned short s) {
    return __uint_as_float((unsigned)s << 16);
}

// ---------------- per-feature GRU via bf16 MFMA (round-10 version) --------
__global__ __launch_bounds__(512, 4) void gru_mfma_kernel(
    const float* __restrict__ x, const int* __restrict__ mask,
    const float* __restrict__ Wih, const float* __restrict__ Whh,
    const float* __restrict__ bih, const float* __restrict__ bhh,
    float* __restrict__ emb)
{
    const int d  = blockIdx.x;
    const int b0 = blockIdx.y * 16;
    const int tid = threadIdx.x;
    const int w = tid >> 6;
    const int l = tid & 63;
    const int m = l & 15;
    const int q = l >> 4;

    __shared__ __align__(16) unsigned short hbuf[2][16][136];
    __shared__ float xs_t[TT][16];
    __shared__ int tstar_s[16];

    for (int idx = tid; idx < 16 * TT; idx += 512) {
        int t = idx >> 4, row = idx & 15;
        xs_t[t][row] = x[((size_t)(b0 + row) * TT + t) * DD + d];
    }
    if (tid < 16) {
        int b = b0 + tid, len = 0;
        for (int t = 0; t < TT; ++t) len += mask[b * TT + t];
        int ts = len - 1;
        if (ts < 0) ts = 0;
        if (ts > TT - 1) ts = TT - 1;
        tstar_s[tid] = ts;
    }
    for (int idx = tid; idx < 16 * 136; idx += 512)
        ((unsigned short*)hbuf)[idx] = 0;

    short8_t Wf[3][4];
#pragma unroll
    for (int g = 0; g < 3; ++g) {
        float sc = (g == 2) ? (2.f * LOG2E) : (-LOG2E);
        int kcol = g * HH + 16 * w + m;
        const float* wrow = Whh + ((size_t)d * K3H + kcol) * HH;
#pragma unroll
        for (int kc = 0; kc < 4; ++kc) {
            int j0 = kc * 32 + q * 8;
            float4 w0 = *(const float4*)(wrow + j0);
            float4 w1 = *(const float4*)(wrow + j0 + 4);
            short8_t f;
            f[0] = (short)f2bf(w0.x * sc); f[1] = (short)f2bf(w0.y * sc);
            f[2] = (short)f2bf(w0.z * sc); f[3] = (short)f2bf(w0.w * sc);
            f[4] = (short)f2bf(w1.x * sc); f[5] = (short)f2bf(w1.y * sc);
            f[6] = (short)f2bf(w1.z * sc); f[7] = (short)f2bf(w1.w * sc);
            Wf[g][kc] = f;
        }
    }

    const int hcol0 = 16 * w + q * 4;
    float4 wr4 = *(const float4*)&Wih[d * K3H + hcol0];
    float4 wz4 = *(const float4*)&Wih[d * K3H + HH + hcol0];
    float4 wn4 = *(const float4*)&Wih[d * K3H + 2 * HH + hcol0];
    float4 br4 = *(const float4*)&bih[d * K3H + hcol0];
    float4 bz4 = *(const float4*)&bih[d * K3H + HH + hcol0];
    float4 bni4 = *(const float4*)&bih[d * K3H + 2 * HH + hcol0];
    float4 bhr4 = *(const float4*)&bhh[d * K3H + hcol0];
    float4 bhz4 = *(const float4*)&bhh[d * K3H + HH + hcol0];
    float4 bnh4 = *(const float4*)&bhh[d * K3H + 2 * HH + hcol0];
    float brs[4], bzs[4], bnis[4], bnhs[4], wrs[4], wzs[4], wns[4];
#pragma unroll
    for (int r = 0; r < 4; ++r) {
        wrs[r] = -LOG2E * ((const float*)&wr4)[r];
        wzs[r] = -LOG2E * ((const float*)&wz4)[r];
        wns[r] = 2.f * LOG2E * ((const float*)&wn4)[r];
        brs[r] = -LOG2E * (((const float*)&br4)[r] + ((const float*)&bhr4)[r]);
        bzs[r] = -LOG2E * (((const float*)&bz4)[r] + ((const float*)&bhz4)[r]);
        bnis[r] = 2.f * LOG2E * ((const float*)&bni4)[r];
        bnhs[r] = 2.f * LOG2E * ((const float*)&bnh4)[r];
    }

    float hprev[4];
#pragma unroll
    for (int i = 0; i < 4; ++i) hprev[i] = 0.f;

    __syncthreads();
    const int tstar_m = tstar_s[m];
    float* embp = emb + (((size_t)(b0 + m)) * DD + d) * HH + hcol0;

    for (int t = 0; t < TT; ++t) {
        const unsigned short* hb = &hbuf[t & 1][0][0];
        unsigned short* hbn = &hbuf[(t & 1) ^ 1][0][0];

        short8_t hf[4];
#pragma unroll
        for (int kc = 0; kc < 4; ++kc)
            hf[kc] = *(const short8_t*)(hb + m * 136 + kc * 32 + q * 8);
        float xv = xs_t[t][m];

        float4_t ar = {brs[0], brs[1], brs[2], brs[3]};
        float4_t az = {bzs[0], bzs[1], bzs[2], bzs[3]};
        float4_t an = {bnhs[0], bnhs[1], bnhs[2], bnhs[3]};
#pragma unroll
        for (int kc = 0; kc < 4; ++kc) {
            ar = __builtin_amdgcn_mfma_f32_16x16x32_bf16(Wf[0][kc], hf[kc], ar, 0, 0, 0);
            az = __builtin_amdgcn_mfma_f32_16x16x32_bf16(Wf[1][kc], hf[kc], az, 0, 0, 0);
            an = __builtin_amdgcn_mfma_f32_16x16x32_bf16(Wf[2][kc], hf[kc], an, 0, 0, 0);
        }

        float hn4[4];
#pragma unroll
        for (int reg = 0; reg < 4; ++reg) {
            float grs = fmaf(xv, wrs[reg], ar[reg]);
            float gzs = fmaf(xv, wzs[reg], az[reg]);
            float rg = __builtin_amdgcn_rcpf(1.f + __builtin_amdgcn_exp2f(grs));
            float zg = __builtin_amdgcn_rcpf(1.f + __builtin_amdgcn_exp2f(gzs));
            float gns = fmaf(rg, an[reg], fmaf(xv, wns[reg], bnis[reg]));
            float tn = fmaf(-2.f, __builtin_amdgcn_rcpf(__builtin_amdgcn_exp2f(gns) + 1.f), 1.f);
            float hn = fmaf(zg, hprev[reg] - tn, tn);
            hprev[reg] = hn;
            hn4[reg] = hn;
        }
        uint2 uu;
        uu.x = pack_bf2_hw(hn4[0], hn4[1]);
        uu.y = pack_bf2_hw(hn4[2], hn4[3]);
        *(uint2*)(hbn + m * 136 + hcol0) = uu;
        if (t == tstar_m) {
            float4 hv; hv.x = hn4[0]; hv.y = hn4[1]; hv.z = hn4[2]; hv.w = hn4[3];
            *(float4*)embp = hv;
        }
        __syncthreads();
    }
}

// ============ fused tail v2 (round-9): register weights, 1 block/batch ====
// 512 threads, 8 waves; wave w owns output cols [16w,16w+16).

__device__ __forceinline__ void load_wfrag(const float* __restrict__ Wp, int N,
                                           int col, float scale, int q,
                                           short8_t fr[4])
{
#pragma unroll
    for (int kc = 0; kc < 4; ++kc) {
        const float* p = Wp + (size_t)(kc * 32 + q * 8) * N + col;
        short8_t f;
#pragma unroll
        for (int j = 0; j < 8; ++j)
            f[j] = (short)f2bf(p[(size_t)j * N] * scale);
        fr[kc] = f;
    }
}

__device__ __forceinline__ void load_afrag(const unsigned short (*S)[136],
                                           short8_t Af[4][4], int m16, int q)
{
#pragma unroll
    for (int mt = 0; mt < 4; ++mt)
#pragma unroll
        for (int kc = 0; kc < 4; ++kc)
            Af[mt][kc] = *(const short8_t*)&S[mt * 16 + m16][kc * 32 + q * 8];
}

__device__ __forceinline__ void mm_regw(short8_t Af[4][4], short8_t Bf[4],
                                        float4_t acc[4])
{
#pragma unroll
    for (int mt = 0; mt < 4; ++mt) {
        float4_t a = acc[mt];
#pragma unroll
        for (int kc = 0; kc < 4; ++kc)
            a = __builtin_amdgcn_mfma_f32_16x16x32_bf16(Af[mt][kc], Bf[kc], a, 0, 0, 0);
        acc[mt] = a;
    }
}

__device__ __forceinline__ void zero4(float4_t acc[4]) {
#pragma unroll
    for (int mt = 0; mt < 4; ++mt) acc[mt] = (float4_t){0.f, 0.f, 0.f, 0.f};
}

__device__ __forceinline__ void store_rows(unsigned short (*Dst)[136], float4_t acc[4],
                                           float bv, int relu, int col, int q)
{
#pragma unroll
    for (int mt = 0; mt < 4; ++mt)
#pragma unroll
        for (int reg = 0; reg < 4; ++reg) {
            float v = acc[mt][reg] + bv;
            if (relu) v = fmaxf(v, 0.f);
            Dst[mt * 16 + q * 4 + reg][col] = f2bf(v);
        }
}

__global__ __launch_bounds__(512) void tail_kernel(
    const float* __restrict__ emb,
    const float* __restrict__ Wq, const float* __restrict__ bq,
    const float* __restrict__ Wk, const float* __restrict__ bk,
    const float* __restrict__ Wv, const float* __restrict__ bv,
    const float* __restrict__ Wo, const float* __restrict__ bo,
    const float* __restrict__ W1, const float* __restrict__ b1,
    const float* __restrict__ W2, const float* __restrict__ b2,
    const float* __restrict__ g1, const float* __restrict__ be1,
    const float* __restrict__ g2, const float* __restrict__ be2,
    const float* __restrict__ Fq, const float* __restrict__ fbq,
    const float* __restrict__ Fk, const float* __restrict__ fbk,
    const float* __restrict__ Fv, const float* __restrict__ fbv,
    const float* __restrict__ Fout, const float* __restrict__ fbout,
    float* __restrict__ out)
{
    const int b = blockIdx.x;
    const int tid = threadIdx.x;
    const int w = tid >> 6, l = tid & 63, m16 = l & 15, q = l >> 4;
    const int col = w * 16 + m16;

    __shared__ __align__(16) unsigned short E[64][136];   // emb->o->h1->h2
    __shared__ __align__(16) unsigned short Qs[64][136];  // q->P01->a1lo->fk
    __shared__ __align__(16) unsigned short Ks[64][136];  // k->P23->a1hi->fv
    __shared__ __align__(16) unsigned short Vt[128][72];  // V transposed
    __shared__ float sc4[4][64][66];                      // scores, 4 heads
    __shared__ float lnp[64][8], lnp2[64][8];
    __shared__ float mean_s[64], rs_s[64];
    __shared__ float fq_s[128], fo_s[128], e_s[64], red_s[256];

    const float* embB = emb + (size_t)b * 64 * 128;
    const float SS = 0.17677669529663687f;   // 1/sqrt(32)

    // ---- prefetch QKV weight frags + biases (covers emb staging) ----
    short8_t WqF[4], WkF[4], WvF[4];
    load_wfrag(Wq, 128, col, SS, q, WqF);
    load_wfrag(Wk, 128, col, 1.f, q, WkF);
    load_wfrag(Wv, 128, col, 1.f, q, WvF);
    float bqv = bq[col] * SS, bkv = bk[col], bvv = bv[col];

    // ---- stage emb fp32 -> bf16 ----
    for (int it = tid; it < 2048; it += 512) {
        int r = it >> 5, c4 = (it & 31) << 2;
        float4 a = *(const float4*)&embB[r * 128 + c4];
        uint2 p; p.x = pack_bf2(a.x, a.y); p.y = pack_bf2(a.z, a.w);
        *(uint2*)&E[r][c4] = p;
    }
    __syncthreads();                                   // B0

    short8_t Af[4][4];
    float4_t acc[4];
    load_afrag(E, Af, m16, q);

    // ---- QKV ----
    zero4(acc); mm_regw(Af, WqF, acc); store_rows(Qs, acc, bqv, 0, col, q);
    zero4(acc); mm_regw(Af, WkF, acc); store_rows(Ks, acc, bkv, 0, col, q);
    zero4(acc); mm_regw(Af, WvF, acc);
#pragma unroll
    for (int mt = 0; mt < 4; ++mt) {   // V transposed: Vt[col][row]
        uint2 pk;
        pk.x = pack_bf2(acc[mt][0] + bvv, acc[mt][1] + bvv);
        pk.y = pack_bf2(acc[mt][2] + bvv, acc[mt][3] + bvv);
        *(uint2*)&Vt[col][mt * 16 + q * 4] = pk;
    }
    __syncthreads();                                   // B1

    // ---- prefetch Wo, W1 frags (covers attention) ----
    short8_t WoF[4], W1aF[4], W1bF[4];
    load_wfrag(Wo, 128, col, 1.f, q, WoF);
    load_wfrag(W1, 256, col, 1.f, q, W1aF);
    load_wfrag(W1, 256, 128 + col, 1.f, q, W1bF);
    float bov = bo[col], b1a = b1[col], b1b = b1[128 + col];
    float g1v = g1[col], be1v = be1[col];

    // ---- scores, all 4 heads ----
    {
        int hd = w >> 1, ntb = (w & 1) * 2;
#pragma unroll
        for (int mt = 0; mt < 4; ++mt) {
            short8_t Aq = *(const short8_t*)&Qs[mt * 16 + m16][hd * 32 + q * 8];
#pragma unroll
            for (int nn = 0; nn < 2; ++nn) {
                int nt = ntb + nn;
                short8_t Bk = *(const short8_t*)&Ks[nt * 16 + m16][hd * 32 + q * 8];
                float4_t a = {0.f, 0.f, 0.f, 0.f};
                a = __builtin_amdgcn_mfma_f32_16x16x32_bf16(Aq, Bk, a, 0, 0, 0);
#pragma unroll
                for (int reg = 0; reg < 4; ++reg)
                    sc4[hd][mt * 16 + q * 4 + reg][nt * 16 + m16] = a[reg];
            }
        }
    }
    __syncthreads();                                   // B2

    // ---- softmax all heads; P (bf16, 1/sum folded) -> Qs/Ks ----
    {
        int pr = tid >> 1, hd2 = pr >> 6, row = pr & 63, half = (tid & 1) * 32;
        float v[32]; float mx = -1e30f;
#pragma unroll
        for (int c = 0; c < 32; ++c) { v[c] = sc4[hd2][row][half + c]; mx = fmaxf(mx, v[c]); }
        mx = fmaxf(mx, __shfl_xor(mx, 1));
        float sum = 0.f;
#pragma unroll
        for (int c = 0; c < 32; ++c) { v[c] = __expf(v[c] - mx); sum += v[c]; }
        sum += __shfl_xor(sum, 1);
        float inv = __builtin_amdgcn_rcpf(sum);
        unsigned short (*Pd)[136] = (hd2 < 2) ? Qs : Ks;
        int cb = (hd2 & 1) * 64 + half;
#pragma unroll
        for (int c = 0; c < 16; ++c)
            *(unsigned*)&Pd[row][cb + 2 * c] = pack_bf2(v[2 * c] * inv, v[2 * c + 1] * inv);
    }
    __syncthreads();                                   // B3

    // ---- PV via MFMA (K=64), O -> E ----
    {
        int hd = w >> 1, nt = w & 1;
        const unsigned short (*P)[136] = (hd < 2) ? (const unsigned short (*)[136])Qs
                                                  : (const unsigned short (*)[136])Ks;
        int pb = (hd & 1) * 64;
        int vrow = hd * 32 + nt * 16 + m16;
        short8_t B0f = *(const short8_t*)&Vt[vrow][q * 8];
        short8_t B1f = *(const short8_t*)&Vt[vrow][32 + q * 8];
#pragma unroll
        for (int mt = 0; mt < 4; ++mt) {
            short8_t A0 = *(const short8_t*)&P[mt * 16 + m16][pb + q * 8];
            short8_t A1 = *(const short8_t*)&P[mt * 16 + m16][pb + 32 + q * 8];
            float4_t a = {0.f, 0.f, 0.f, 0.f};
            a = __builtin_amdgcn_mfma_f32_16x16x32_bf16(A0, B0f, a, 0, 0, 0);
            a = __builtin_amdgcn_mfma_f32_16x16x32_bf16(A1, B1f, a, 0, 0, 0);
#pragma unroll
            for (int reg = 0; reg < 4; ++reg)
                E[mt * 16 + q * 4 + reg][vrow] = f2bf(a[reg]);
        }
    }
    __syncthreads();                                   // B4

    // ---- prefetch W2, Fk, Fv frags (covers Wo/LN1/FFN1) ----
    short8_t W2aF[4], W2bF[4], FkF[4], FvF[4];
    load_wfrag(W2, 128, col, 1.f, q, W2aF);
    load_wfrag(W2 + (size_t)128 * 128, 128, col, 1.f, q, W2bF);
    load_wfrag(Fk, 128, col, 1.f, q, FkF);
    load_wfrag(Fv, 128, col, 1.f, q, FvF);
    float b2v = b2[col], fbkv = fbk[col], fbvv = fbv[col];
    float g2v = g2[col], be2v = be2[col];

    // ---- Wo + residual(emb fp32) + LN1; h1 kept in regs ----
    load_afrag(E, Af, m16, q);
    zero4(acc); mm_regw(Af, WoF, acc);
    float h1v[4][4];
#pragma unroll
    for (int mt = 0; mt < 4; ++mt)
#pragma unroll
        for (int reg = 0; reg < 4; ++reg) {
            int row = mt * 16 + q * 4 + reg;
            h1v[mt][reg] = acc[mt][reg] + bov + embB[(size_t)row * 128 + col];
        }
#pragma unroll
    for (int mt = 0; mt < 4; ++mt)
#pragma unroll
        for (int reg = 0; reg < 4; ++reg) {
            float s = h1v[mt][reg], s2 = s * s;
            s += __shfl_xor(s, 1); s += __shfl_xor(s, 2); s += __shfl_xor(s, 4); s += __shfl_xor(s, 8);
            s2 += __shfl_xor(s2, 1); s2 += __shfl_xor(s2, 2); s2 += __shfl_xor(s2, 4); s2 += __shfl_xor(s2, 8);
            if (m16 == 0) { int row = mt * 16 + q * 4 + reg; lnp[row][w] = s; lnp2[row][w] = s2; }
        }
    __syncthreads();                                   // B5
    if (tid < 64) {
        float s = 0.f, s2 = 0.f;
#pragma unroll
        for (int k = 0; k < 8; ++k) { s += lnp[tid][k]; s2 += lnp2[tid][k]; }
        float mn = s * (1.f / 128.f);
        mean_s[tid] = mn;
        rs_s[tid] = rsqrtf(s2 * (1.f / 128.f) - mn * mn + 1e-5f);
    }
    __syncthreads();                                   // B6
#pragma unroll
    for (int mt = 0; mt < 4; ++mt)
#pragma unroll
        for (int reg = 0; reg < 4; ++reg) {
            int row = mt * 16 + q * 4 + reg;
            float hv = (h1v[mt][reg] - mean_s[row]) * rs_s[row] * g1v + be1v;
            h1v[mt][reg] = hv;
            E[row][col] = f2bf(hv);
        }
    __syncthreads();                                   // B7

    // ---- FFN1: a1 = relu(h1 @ W1 + b1) -> Qs (lo), Ks (hi) ----
    load_afrag(E, Af, m16, q);
    zero4(acc); mm_regw(Af, W1aF, acc); store_rows(Qs, acc, b1a, 1, col, q);
    zero4(acc); mm_regw(Af, W1bF, acc); store_rows(Ks, acc, b1b, 1, col, q);
    __syncthreads();                                   // B8

    // ---- FFN2 (K=256) + residual(h1 regs) + LN2 -> E (h2) ----
    {
        short8_t AfQ[4][4], AfK[4][4];
        load_afrag(Qs, AfQ, m16, q);
        load_afrag(Ks, AfK, m16, q);
        zero4(acc); mm_regw(AfQ, W2aF, acc); mm_regw(AfK, W2bF, acc);
    }
#pragma unroll
    for (int mt = 0; mt < 4; ++mt)
#pragma unroll
        for (int reg = 0; reg < 4; ++reg)
            h1v[mt][reg] = acc[mt][reg] + b2v + h1v[mt][reg];
#pragma unroll
    for (int mt = 0; mt < 4; ++mt)
#pragma unroll
        for (int reg = 0; reg < 4; ++reg) {
            float s = h1v[mt][reg], s2 = s * s;
            s += __shfl_xor(s, 1); s += __shfl_xor(s, 2); s += __shfl_xor(s, 4); s += __shfl_xor(s, 8);
            s2 += __shfl_xor(s2, 1); s2 += __shfl_xor(s2, 2); s2 += __shfl_xor(s2, 4); s2 += __shfl_xor(s2, 8);
            if (m16 == 0) { int row = mt * 16 + q * 4 + reg; lnp[row][w] = s; lnp2[row][w] = s2; }
        }
    __syncthreads();                                   // B9
    if (tid < 64) {
        float s = 0.f, s2 = 0.f;
#pragma unroll
        for (int k = 0; k < 8; ++k) { s += lnp[tid][k]; s2 += lnp2[tid][k]; }
        float mn = s * (1.f / 128.f);
        mean_s[tid] = mn;
        rs_s[tid] = rsqrtf(s2 * (1.f / 128.f) - mn * mn + 1e-5f);
    }
    __syncthreads();                                   // B10
#pragma unroll
    for (int mt = 0; mt < 4; ++mt)
#pragma unroll
        for (int reg = 0; reg < 4; ++reg) {
            int row = mt * 16 + q * 4 + reg;
            float hv = (h1v[mt][reg] - mean_s[row]) * rs_s[row] * g2v + be2v;
            E[row][col] = f2bf(hv);   // h2
        }
    __syncthreads();                                   // B11

    // ---- final projections: fk -> Qs, fv -> Ks; fq 4-thr/col ----
    load_afrag(E, Af, m16, q);
    zero4(acc); mm_regw(Af, FkF, acc); store_rows(Qs, acc, fbkv, 0, col, q);
    zero4(acc); mm_regw(Af, FvF, acc); store_rows(Ks, acc, fbvv, 0, col, q);
    {
        int co = tid >> 2, sub = tid & 3;
        float a2 = 0.f;
#pragma unroll 8
        for (int mm2 = sub * 32; mm2 < sub * 32 + 32; ++mm2)
            a2 = fmaf(bf2f(E[63][mm2]), Fq[(size_t)mm2 * 128 + co], a2);
        a2 += __shfl_xor(a2, 1);
        a2 += __shfl_xor(a2, 2);
        if (sub == 0) fq_s[co] = a2 + fbq[co];
    }
    if (tid < 128) fo_s[tid] = Fout[tid];
    __syncthreads();                                   // B12

    {   // e[dd] = tanh(fq + fk[dd]) . Fout + fbout
        int dd = tid >> 3, c8 = tid & 7;
        float p = 0.f;
#pragma unroll
        for (int c = 0; c < 16; ++c) {
            int cc = c8 * 16 + c;
            float t = fq_s[cc] + bf2f(Qs[dd][cc]);
            float tn = 1.f - 2.f * __builtin_amdgcn_rcpf(
                __builtin_amdgcn_exp2f(2.f * LOG2E * t) + 1.f);
            p = fmaf(tn, fo_s[cc], p);
        }
        p += __shfl_xor(p, 1); p += __shfl_xor(p, 2); p += __shfl_xor(p, 4);
        if (c8 == 0) e_s[dd] = p + fbout[0];
    }
    __syncthreads();                                   // B13
    if (tid < 64) {
        float e = e_s[tid], mx = e;
        for (int o = 32; o; o >>= 1) mx = fmaxf(mx, __shfl_xor(mx, o));
        float pe = __expf(e - mx);
        float s = pe;
        for (int o = 32; o; o >>= 1) s += __shfl_xor(s, o);
        e_s[tid] = pe / s;
    }
    __syncthreads();                                   // B14
    if (tid < 256) {
        int c2 = tid & 127, rg2 = tid >> 7;
        float a = 0.f;
        for (int d2 = rg2 * 32; d2 < rg2 * 32 + 32; ++d2)
            a = fmaf(e_s[d2], bf2f(Ks[d2][c2]), a);
        red_s[tid] = a;
    }
    __syncthreads();                                   // B15
    if (tid < 128)
        out[(size_t)b * 128 + tid] = red_s[tid] + red_s[tid + 128];
}

// ---------------- launch ---------------------------------------------------
extern "C" void kernel_launch(void* const* d_in, const int* in_sizes, int n_in,
                              void* d_out, int out_size, void* d_ws, size_t ws_size,
                              hipStream_t stream)
{
    const float* x    = (const float*)d_in[0];
    const int*   mask = (const int*)d_in[1];
    const float* Wih  = (const float*)d_in[2];
    const float* Whh  = (const float*)d_in[3];
    const float* bih  = (const float*)d_in[4];
    const float* bhh  = (const float*)d_in[5];
    const float* Wq = (const float*)d_in[6];   const float* bq = (const float*)d_in[7];
    const float* Wk = (const float*)d_in[8];   const float* bk = (const float*)d_in[9];
    const float* Wv = (const float*)d_in[10];  const float* bv = (const float*)d_in[11];
    const float* Wo = (const float*)d_in[12];  const float* bo = (const float*)d_in[13];
    const float* W1 = (const float*)d_in[14];  const float* b1 = (const float*)d_in[15];
    const float* W2 = (const float*)d_in[16];  const float* b2 = (const float*)d_in[17];
    const float* g1 = (const float*)d_in[18];  const float* be1 = (const float*)d_in[19];
    const float* g2 = (const float*)d_in[20];  const float* be2 = (const float*)d_in[21];
    const float* Fq = (const float*)d_in[22];  const float* fbq = (const float*)d_in[23];
    const float* Fk = (const float*)d_in[24];  const float* fbk = (const float*)d_in[25];
    const float* Fv = (const float*)d_in[26];  const float* fbv = (const float*)d_in[27];
    const float* Fout = (const float*)d_in[28]; const float* fbout = (const float*)d_in[29];
    float* out = (float*)d_out;
    float* ws  = (float*)d_ws;

    float* emb = ws;   // 1048576 floats

    gru_mfma_kernel<<<dim3(DD, BB / 16), 512, 0, stream>>>(x, mask, Wih, Whh, bih, bhh, emb);
    tail_kernel<<<BB, 512, 0, stream>>>(
        emb, Wq, bq, Wk, bk, Wv, bv, Wo, bo, W1, b1, W2, b2,
        g1, be1, g2, be2, Fq, fbq, Fk, fbk, Fv, fbv, Fout, fbout, out);
}

// Round 12
// 244.243 us; speedup vs baseline: 1.0302x; 1.0139x over previous
//
#include <hip/hip_runtime.h>
#include <hip/hip_bf16.h>
#include <math.h>

#define BB 128
#define TT 64
#define DD 64
#define HH 128
#define NHH 4
#define K3H 384        // 3*H

typedef __attribute__((ext_vector_type(8))) short short8_t;   // 8 bf16
typedef __attribute__((ext_vector_type(4))) float float4_t;

#define LOG2E 1.4426950408889634f

__device__ __forceinline__ unsigned short f2bf(float f) {
    unsigned int u = __float_as_uint(f);
    u += 0x7fffu + ((u >> 16) & 1u);      // RNE
    return (unsigned short)(u >> 16);
}

__device__ __forceinline__ unsigned pack_bf2(float lo, float hi) {
    return (unsigned)f2bf(lo) | ((unsigned)f2bf(hi) << 16);
}

__device__ __forceinline__ unsigned pack_bf2_hw(float lo, float hi) {
    __hip_bfloat162 p = __float22bfloat162_rn(make_float2(lo, hi));
    unsigned u;
    __builtin_memcpy(&u, &p, 4);
    return u;
}

__device__ __forceinline__ float bf2f(unsigned short s) {
    return __uint_as_float((unsigned)s << 16);
}

// packed-pair fp32 helpers (SLP -> v_pk_fma_f32 / v_pk_add_f32)
__device__ __forceinline__ float2 pk_fma(float2 a, float2 b, float2 c) {
    return make_float2(fmaf(a.x, b.x, c.x), fmaf(a.y, b.y, c.y));
}
__device__ __forceinline__ float2 pk_sub(float2 a, float2 b) {
    return make_float2(a.x - b.x, a.y - b.y);
}

// ---------------- per-feature GRU via bf16 MFMA (packed epilogue) ---------
__global__ __launch_bounds__(512, 4) void gru_mfma_kernel(
    const float* __restrict__ x, const int* __restrict__ mask,
    const float* __restrict__ Wih, const float* __restrict__ Whh,
    const float* __restrict__ bih, const float* __restrict__ bhh,
    float* __restrict__ emb)
{
    const int d  = blockIdx.x;
    const int b0 = blockIdx.y * 16;
    const int tid = threadIdx.x;
    const int w = tid >> 6;
    const int l = tid & 63;
    const int m = l & 15;
    const int q = l >> 4;

    __shared__ __align__(16) unsigned short hbuf[2][16][136];
    __shared__ float xs_t[TT][16];
    __shared__ int tstar_s[16];

    for (int idx = tid; idx < 16 * TT; idx += 512) {
        int t = idx >> 4, row = idx & 15;
        xs_t[t][row] = x[((size_t)(b0 + row) * TT + t) * DD + d];
    }
    if (tid < 16) {
        int b = b0 + tid, len = 0;
        for (int t = 0; t < TT; ++t) len += mask[b * TT + t];
        int ts = len - 1;
        if (ts < 0) ts = 0;
        if (ts > TT - 1) ts = TT - 1;
        tstar_s[tid] = ts;
    }
    for (int idx = tid; idx < 16 * 136; idx += 512)
        ((unsigned short*)hbuf)[idx] = 0;

    short8_t Wf[3][4];
#pragma unroll
    for (int g = 0; g < 3; ++g) {
        float sc = (g == 2) ? (2.f * LOG2E) : (-LOG2E);
        int kcol = g * HH + 16 * w + m;
        const float* wrow = Whh + ((size_t)d * K3H + kcol) * HH;
#pragma unroll
        for (int kc = 0; kc < 4; ++kc) {
            int j0 = kc * 32 + q * 8;
            float4 w0 = *(const float4*)(wrow + j0);
            float4 w1 = *(const float4*)(wrow + j0 + 4);
            short8_t f;
            f[0] = (short)f2bf(w0.x * sc); f[1] = (short)f2bf(w0.y * sc);
            f[2] = (short)f2bf(w0.z * sc); f[3] = (short)f2bf(w0.w * sc);
            f[4] = (short)f2bf(w1.x * sc); f[5] = (short)f2bf(w1.y * sc);
            f[6] = (short)f2bf(w1.z * sc); f[7] = (short)f2bf(w1.w * sc);
            Wf[g][kc] = f;
        }
    }

    const int hcol0 = 16 * w + q * 4;
    float4 wr4 = *(const float4*)&Wih[d * K3H + hcol0];
    float4 wz4 = *(const float4*)&Wih[d * K3H + HH + hcol0];
    float4 wn4 = *(const float4*)&Wih[d * K3H + 2 * HH + hcol0];
    float4 br4 = *(const float4*)&bih[d * K3H + hcol0];
    float4 bz4 = *(const float4*)&bih[d * K3H + HH + hcol0];
    float4 bni4 = *(const float4*)&bih[d * K3H + 2 * HH + hcol0];
    float4 bhr4 = *(const float4*)&bhh[d * K3H + hcol0];
    float4 bhz4 = *(const float4*)&bhh[d * K3H + HH + hcol0];
    float4 bnh4 = *(const float4*)&bhh[d * K3H + 2 * HH + hcol0];
    float brs[4], bzs[4], bnis[4], bnhs[4], wrs[4], wzs[4], wns[4];
#pragma unroll
    for (int r = 0; r < 4; ++r) {
        wrs[r] = -LOG2E * ((const float*)&wr4)[r];
        wzs[r] = -LOG2E * ((const float*)&wz4)[r];
        wns[r] = 2.f * LOG2E * ((const float*)&wn4)[r];
        brs[r] = -LOG2E * (((const float*)&br4)[r] + ((const float*)&bhr4)[r]);
        bzs[r] = -LOG2E * (((const float*)&bz4)[r] + ((const float*)&bhz4)[r]);
        bnis[r] = 2.f * LOG2E * ((const float*)&bni4)[r];
        bnhs[r] = 2.f * LOG2E * ((const float*)&bnh4)[r];
    }

    float hprev[4];
#pragma unroll
    for (int i = 0; i < 4; ++i) hprev[i] = 0.f;

    __syncthreads();
    const int tstar_m = tstar_s[m];
    float* embp = emb + (((size_t)(b0 + m)) * DD + d) * HH + hcol0;

    for (int t = 0; t < TT; ++t) {
        const unsigned short* hb = &hbuf[t & 1][0][0];
        unsigned short* hbn = &hbuf[(t & 1) ^ 1][0][0];

        short8_t hf[4];
#pragma unroll
        for (int kc = 0; kc < 4; ++kc)
            hf[kc] = *(const short8_t*)(hb + m * 136 + kc * 32 + q * 8);
        float xv = xs_t[t][m];

        float4_t ar = {brs[0], brs[1], brs[2], brs[3]};
        float4_t az = {bzs[0], bzs[1], bzs[2], bzs[3]};
        float4_t an = {bnhs[0], bnhs[1], bnhs[2], bnhs[3]};
#pragma unroll
        for (int kc = 0; kc < 4; ++kc) {
            ar = __builtin_amdgcn_mfma_f32_16x16x32_bf16(Wf[0][kc], hf[kc], ar, 0, 0, 0);
            az = __builtin_amdgcn_mfma_f32_16x16x32_bf16(Wf[1][kc], hf[kc], az, 0, 0, 0);
            an = __builtin_amdgcn_mfma_f32_16x16x32_bf16(Wf[2][kc], hf[kc], an, 0, 0, 0);
        }

        float hn4[4];
        float2 xv2 = make_float2(xv, xv);
#pragma unroll
        for (int pp = 0; pp < 2; ++pp) {
            const int r0 = 2 * pp, r1 = r0 + 1;
            float2 grs = pk_fma(xv2, make_float2(wrs[r0], wrs[r1]),
                                make_float2(ar[r0], ar[r1]));
            float2 gzs = pk_fma(xv2, make_float2(wzs[r0], wzs[r1]),
                                make_float2(az[r0], az[r1]));
            float2 rg = make_float2(
                __builtin_amdgcn_rcpf(1.f + __builtin_amdgcn_exp2f(grs.x)),
                __builtin_amdgcn_rcpf(1.f + __builtin_amdgcn_exp2f(grs.y)));
            float2 zg = make_float2(
                __builtin_amdgcn_rcpf(1.f + __builtin_amdgcn_exp2f(gzs.x)),
                __builtin_amdgcn_rcpf(1.f + __builtin_amdgcn_exp2f(gzs.y)));
            float2 gns = pk_fma(rg, make_float2(an[r0], an[r1]),
                                pk_fma(xv2, make_float2(wns[r0], wns[r1]),
                                       make_float2(bnis[r0], bnis[r1])));
            float2 tn = make_float2(
                fmaf(-2.f, __builtin_amdgcn_rcpf(__builtin_amdgcn_exp2f(gns.x) + 1.f), 1.f),
                fmaf(-2.f, __builtin_amdgcn_rcpf(__builtin_amdgcn_exp2f(gns.y) + 1.f), 1.f));
            float2 hp = make_float2(hprev[r0], hprev[r1]);
            float2 hn = pk_fma(zg, pk_sub(hp, tn), tn);
            hprev[r0] = hn.x; hprev[r1] = hn.y;
            hn4[r0] = hn.x; hn4[r1] = hn.y;
        }
        uint2 uu;
        uu.x = pack_bf2_hw(hn4[0], hn4[1]);
        uu.y = pack_bf2_hw(hn4[2], hn4[3]);
        *(uint2*)(hbn + m * 136 + hcol0) = uu;
        if (t == tstar_m) {
            float4 hv; hv.x = hn4[0]; hv.y = hn4[1]; hv.z = hn4[2]; hv.w = hn4[3];
            *(float4*)embp = hv;
        }
        __syncthreads();
    }
}

// ============ fused tail v2 (round-11, unchanged) =========================
__device__ __forceinline__ void load_wfrag(const float* __restrict__ Wp, int N,
                                           int col, float scale, int q,
                                           short8_t fr[4])
{
#pragma unroll
    for (int kc = 0; kc < 4; ++kc) {
        const float* p = Wp + (size_t)(kc * 32 + q * 8) * N + col;
        short8_t f;
#pragma unroll
        for (int j = 0; j < 8; ++j)
            f[j] = (short)f2bf(p[(size_t)j * N] * scale);
        fr[kc] = f;
    }
}

__device__ __forceinline__ void load_afrag(const unsigned short (*S)[136],
                                           short8_t Af[4][4], int m16, int q)
{
#pragma unroll
    for (int mt = 0; mt < 4; ++mt)
#pragma unroll
        for (int kc = 0; kc < 4; ++kc)
            Af[mt][kc] = *(const short8_t*)&S[mt * 16 + m16][kc * 32 + q * 8];
}

__device__ __forceinline__ void mm_regw(short8_t Af[4][4], short8_t Bf[4],
                                        float4_t acc[4])
{
#pragma unroll
    for (int mt = 0; mt < 4; ++mt) {
        float4_t a = acc[mt];
#pragma unroll
        for (int kc = 0; kc < 4; ++kc)
            a = __builtin_amdgcn_mfma_f32_16x16x32_bf16(Af[mt][kc], Bf[kc], a, 0, 0, 0);
        acc[mt] = a;
    }
}

__device__ __forceinline__ void zero4(float4_t acc[4]) {
#pragma unroll
    for (int mt = 0; mt < 4; ++mt) acc[mt] = (float4_t){0.f, 0.f, 0.f, 0.f};
}

__device__ __forceinline__ void store_rows(unsigned short (*Dst)[136], float4_t acc[4],
                                           float bv, int relu, int col, int q)
{
#pragma unroll
    for (int mt = 0; mt < 4; ++mt)
#pragma unroll
        for (int reg = 0; reg < 4; ++reg) {
            float v = acc[mt][reg] + bv;
            if (relu) v = fmaxf(v, 0.f);
            Dst[mt * 16 + q * 4 + reg][col] = f2bf(v);
        }
}

__global__ __launch_bounds__(512) void tail_kernel(
    const float* __restrict__ emb,
    const float* __restrict__ Wq, const float* __restrict__ bq,
    const float* __restrict__ Wk, const float* __restrict__ bk,
    const float* __restrict__ Wv, const float* __restrict__ bv,
    const float* __restrict__ Wo, const float* __restrict__ bo,
    const float* __restrict__ W1, const float* __restrict__ b1,
    const float* __restrict__ W2, const float* __restrict__ b2,
    const float* __restrict__ g1, const float* __restrict__ be1,
    const float* __restrict__ g2, const float* __restrict__ be2,
    const float* __restrict__ Fq, const float* __restrict__ fbq,
    const float* __restrict__ Fk, const float* __restrict__ fbk,
    const float* __restrict__ Fv, const float* __restrict__ fbv,
    const float* __restrict__ Fout, const float* __restrict__ fbout,
    float* __restrict__ out)
{
    const int b = blockIdx.x;
    const int tid = threadIdx.x;
    const int w = tid >> 6, l = tid & 63, m16 = l & 15, q = l >> 4;
    const int col = w * 16 + m16;

    __shared__ __align__(16) unsigned short E[64][136];   // emb->o->h1->h2
    __shared__ __align__(16) unsigned short Qs[64][136];  // q->P01->a1lo->fk
    __shared__ __align__(16) unsigned short Ks[64][136];  // k->P23->a1hi->fv
    __shared__ __align__(16) unsigned short Vt[128][72];  // V transposed
    __shared__ float sc4[4][64][66];                      // scores, 4 heads
    __shared__ float lnp[64][8], lnp2[64][8];
    __shared__ float mean_s[64], rs_s[64];
    __shared__ float fq_s[128], fo_s[128], e_s[64], red_s[256];

    const float* embB = emb + (size_t)b * 64 * 128;
    const float SS = 0.17677669529663687f;   // 1/sqrt(32)

    short8_t WqF[4], WkF[4], WvF[4];
    load_wfrag(Wq, 128, col, SS, q, WqF);
    load_wfrag(Wk, 128, col, 1.f, q, WkF);
    load_wfrag(Wv, 128, col, 1.f, q, WvF);
    float bqv = bq[col] * SS, bkv = bk[col], bvv = bv[col];

    for (int it = tid; it < 2048; it += 512) {
        int r = it >> 5, c4 = (it & 31) << 2;
        float4 a = *(const float4*)&embB[r * 128 + c4];
        uint2 p; p.x = pack_bf2(a.x, a.y); p.y = pack_bf2(a.z, a.w);
        *(uint2*)&E[r][c4] = p;
    }
    __syncthreads();                                   // B0

    short8_t Af[4][4];
    float4_t acc[4];
    load_afrag(E, Af, m16, q);

    zero4(acc); mm_regw(Af, WqF, acc); store_rows(Qs, acc, bqv, 0, col, q);
    zero4(acc); mm_regw(Af, WkF, acc); store_rows(Ks, acc, bkv, 0, col, q);
    zero4(acc); mm_regw(Af, WvF, acc);
#pragma unroll
    for (int mt = 0; mt < 4; ++mt) {
        uint2 pk;
        pk.x = pack_bf2(acc[mt][0] + bvv, acc[mt][1] + bvv);
        pk.y = pack_bf2(acc[mt][2] + bvv, acc[mt][3] + bvv);
        *(uint2*)&Vt[col][mt * 16 + q * 4] = pk;
    }
    __syncthreads();                                   // B1

    short8_t WoF[4], W1aF[4], W1bF[4];
    load_wfrag(Wo, 128, col, 1.f, q, WoF);
    load_wfrag(W1, 256, col, 1.f, q, W1aF);
    load_wfrag(W1, 256, 128 + col, 1.f, q, W1bF);
    float bov = bo[col], b1a = b1[col], b1b = b1[128 + col];
    float g1v = g1[col], be1v = be1[col];

    {
        int hd = w >> 1, ntb = (w & 1) * 2;
#pragma unroll
        for (int mt = 0; mt < 4; ++mt) {
            short8_t Aq = *(const short8_t*)&Qs[mt * 16 + m16][hd * 32 + q * 8];
#pragma unroll
            for (int nn = 0; nn < 2; ++nn) {
                int nt = ntb + nn;
                short8_t Bk = *(const short8_t*)&Ks[nt * 16 + m16][hd * 32 + q * 8];
                float4_t a = {0.f, 0.f, 0.f, 0.f};
                a = __builtin_amdgcn_mfma_f32_16x16x32_bf16(Aq, Bk, a, 0, 0, 0);
#pragma unroll
                for (int reg = 0; reg < 4; ++reg)
                    sc4[hd][mt * 16 + q * 4 + reg][nt * 16 + m16] = a[reg];
            }
        }
    }
    __syncthreads();                                   // B2

    {
        int pr = tid >> 1, hd2 = pr >> 6, row = pr & 63, half = (tid & 1) * 32;
        float v[32]; float mx = -1e30f;
#pragma unroll
        for (int c = 0; c < 32; ++c) { v[c] = sc4[hd2][row][half + c]; mx = fmaxf(mx, v[c]); }
        mx = fmaxf(mx, __shfl_xor(mx, 1));
        float sum = 0.f;
#pragma unroll
        for (int c = 0; c < 32; ++c) { v[c] = __expf(v[c] - mx); sum += v[c]; }
        sum += __shfl_xor(sum, 1);
        float inv = __builtin_amdgcn_rcpf(sum);
        unsigned short (*Pd)[136] = (hd2 < 2) ? Qs : Ks;
        int cb = (hd2 & 1) * 64 + half;
#pragma unroll
        for (int c = 0; c < 16; ++c)
            *(unsigned*)&Pd[row][cb + 2 * c] = pack_bf2(v[2 * c] * inv, v[2 * c + 1] * inv);
    }
    __syncthreads();                                   // B3

    {
        int hd = w >> 1, nt = w & 1;
        const unsigned short (*P)[136] = (hd < 2) ? (const unsigned short (*)[136])Qs
                                                  : (const unsigned short (*)[136])Ks;
        int pb = (hd & 1) * 64;
        int vrow = hd * 32 + nt * 16 + m16;
        short8_t B0f = *(const short8_t*)&Vt[vrow][q * 8];
        short8_t B1f = *(const short8_t*)&Vt[vrow][32 + q * 8];
#pragma unroll
        for (int mt = 0; mt < 4; ++mt) {
            short8_t A0 = *(const short8_t*)&P[mt * 16 + m16][pb + q * 8];
            short8_t A1 = *(const short8_t*)&P[mt * 16 + m16][pb + 32 + q * 8];
            float4_t a = {0.f, 0.f, 0.f, 0.f};
            a = __builtin_amdgcn_mfma_f32_16x16x32_bf16(A0, B0f, a, 0, 0, 0);
            a = __builtin_amdgcn_mfma_f32_16x16x32_bf16(A1, B1f, a, 0, 0, 0);
#pragma unroll
            for (int reg = 0; reg < 4; ++reg)
                E[mt * 16 + q * 4 + reg][vrow] = f2bf(a[reg]);
        }
    }
    __syncthreads();                                   // B4

    short8_t W2aF[4], W2bF[4], FkF[4], FvF[4];
    load_wfrag(W2, 128, col, 1.f, q, W2aF);
    load_wfrag(W2 + (size_t)128 * 128, 128, col, 1.f, q, W2bF);
    load_wfrag(Fk, 128, col, 1.f, q, FkF);
    load_wfrag(Fv, 128, col, 1.f, q, FvF);
    float b2v = b2[col], fbkv = fbk[col], fbvv = fbv[col];
    float g2v = g2[col], be2v = be2[col];

    load_afrag(E, Af, m16, q);
    zero4(acc); mm_regw(Af, WoF, acc);
    float h1v[4][4];
#pragma unroll
    for (int mt = 0; mt < 4; ++mt)
#pragma unroll
        for (int reg = 0; reg < 4; ++reg) {
            int row = mt * 16 + q * 4 + reg;
            h1v[mt][reg] = acc[mt][reg] + bov + embB[(size_t)row * 128 + col];
        }
#pragma unroll
    for (int mt = 0; mt < 4; ++mt)
#pragma unroll
        for (int reg = 0; reg < 4; ++reg) {
            float s = h1v[mt][reg], s2 = s * s;
            s += __shfl_xor(s, 1); s += __shfl_xor(s, 2); s += __shfl_xor(s, 4); s += __shfl_xor(s, 8);
            s2 += __shfl_xor(s2, 1); s2 += __shfl_xor(s2, 2); s2 += __shfl_xor(s2, 4); s2 += __shfl_xor(s2, 8);
            if (m16 == 0) { int row = mt * 16 + q * 4 + reg; lnp[row][w] = s; lnp2[row][w] = s2; }
        }
    __syncthreads();                                   // B5
    if (tid < 64) {
        float s = 0.f, s2 = 0.f;
#pragma unroll
        for (int k = 0; k < 8; ++k) { s += lnp[tid][k]; s2 += lnp2[tid][k]; }
        float mn = s * (1.f / 128.f);
        mean_s[tid] = mn;
        rs_s[tid] = rsqrtf(s2 * (1.f / 128.f) - mn * mn + 1e-5f);
    }
    __syncthreads();                                   // B6
#pragma unroll
    for (int mt = 0; mt < 4; ++mt)
#pragma unroll
        for (int reg = 0; reg < 4; ++reg) {
            int row = mt * 16 + q * 4 + reg;
            float hv = (h1v[mt][reg] - mean_s[row]) * rs_s[row] * g1v + be1v;
            h1v[mt][reg] = hv;
            E[row][col] = f2bf(hv);
        }
    __syncthreads();                                   // B7

    load_afrag(E, Af, m16, q);
    zero4(acc); mm_regw(Af, W1aF, acc); store_rows(Qs, acc, b1a, 1, col, q);
    zero4(acc); mm_regw(Af, W1bF, acc); store_rows(Ks, acc, b1b, 1, col, q);
    __syncthreads();                                   // B8

    {
        short8_t AfQ[4][4], AfK[4][4];
        load_afrag(Qs, AfQ, m16, q);
        load_afrag(Ks, AfK, m16, q);
        zero4(acc); mm_regw(AfQ, W2aF, acc); mm_regw(AfK, W2bF, acc);
    }
#pragma unroll
    for (int mt = 0; mt < 4; ++mt)
#pragma unroll
        for (int reg = 0; reg < 4; ++reg)
            h1v[mt][reg] = acc[mt][reg] + b2v + h1v[mt][reg];
#pragma unroll
    for (int mt = 0; mt < 4; ++mt)
#pragma unroll
        for (int reg = 0; reg < 4; ++reg) {
            float s = h1v[mt][reg], s2 = s * s;
            s += __shfl_xor(s, 1); s += __shfl_xor(s, 2); s += __shfl_xor(s, 4); s += __shfl_xor(s, 8);
            s2 += __shfl_xor(s2, 1); s2 += __shfl_xor(s2, 2); s2 += __shfl_xor(s2, 4); s2 += __shfl_xor(s2, 8);
            if (m16 == 0) { int row = mt * 16 + q * 4 + reg; lnp[row][w] = s; lnp2[row][w] = s2; }
        }
    __syncthreads();                                   // B9
    if (tid < 64) {
        float s = 0.f, s2 = 0.f;
#pragma unroll
        for (int k = 0; k < 8; ++k) { s += lnp[tid][k]; s2 += lnp2[tid][k]; }
        float mn = s * (1.f / 128.f);
        mean_s[tid] = mn;
        rs_s[tid] = rsqrtf(s2 * (1.f / 128.f) - mn * mn + 1e-5f);
    }
    __syncthreads();                                   // B10
#pragma unroll
    for (int mt = 0; mt < 4; ++mt)
#pragma unroll
        for (int reg = 0; reg < 4; ++reg) {
            int row = mt * 16 + q * 4 + reg;
            float hv = (h1v[mt][reg] - mean_s[row]) * rs_s[row] * g2v + be2v;
            E[row][col] = f2bf(hv);   // h2
        }
    __syncthreads();                                   // B11

    load_afrag(E, Af, m16, q);
    zero4(acc); mm_regw(Af, FkF, acc); store_rows(Qs, acc, fbkv, 0, col, q);
    zero4(acc); mm_regw(Af, FvF, acc); store_rows(Ks, acc, fbvv, 0, col, q);
    {
        int co = tid >> 2, sub = tid & 3;
        float a2 = 0.f;
#pragma unroll 8
        for (int mm2 = sub * 32; mm2 < sub * 32 + 32; ++mm2)
            a2 = fmaf(bf2f(E[63][mm2]), Fq[(size_t)mm2 * 128 + co], a2);
        a2 += __shfl_xor(a2, 1);
        a2 += __shfl_xor(a2, 2);
        if (sub == 0) fq_s[co] = a2 + fbq[co];
    }
    if (tid < 128) fo_s[tid] = Fout[tid];
    __syncthreads();                                   // B12

    {
        int dd = tid >> 3, c8 = tid & 7;
        float p = 0.f;
#pragma unroll
        for (int c = 0; c < 16; ++c) {
            int cc = c8 * 16 + c;
            float t = fq_s[cc] + bf2f(Qs[dd][cc]);
            float tn = 1.f - 2.f * __builtin_amdgcn_rcpf(
                __builtin_amdgcn_exp2f(2.f * LOG2E * t) + 1.f);
            p = fmaf(tn, fo_s[cc], p);
        }
        p += __shfl_xor(p, 1); p += __shfl_xor(p, 2); p += __shfl_xor(p, 4);
        if (c8 == 0) e_s[dd] = p + fbout[0];
    }
    __syncthreads();                                   // B13
    if (tid < 64) {
        float e = e_s[tid], mx = e;
        for (int o = 32; o; o >>= 1) mx = fmaxf(mx, __shfl_xor(mx, o));
        float pe = __expf(e - mx);
        float s = pe;
        for (int o = 32; o; o >>= 1) s += __shfl_xor(s, o);
        e_s[tid] = pe / s;
    }
    __syncthreads();                                   // B14
    if (tid < 256) {
        int c2 = tid & 127, rg2 = tid >> 7;
        float a = 0.f;
        for (int d2 = rg2 * 32; d2 < rg2 * 32 + 32; ++d2)
            a = fmaf(e_s[d2], bf2f(Ks[d2][c2]), a);
        red_s[tid] = a;
    }
    __syncthreads();                                   // B15
    if (tid < 128)
        out[(size_t)b * 128 + tid] = red_s[tid] + red_s[tid + 128];
}

// ---------------- launch ---------------------------------------------------
extern "C" void kernel_launch(void* const* d_in, const int* in_sizes, int n_in,
                              void* d_out, int out_size, void* d_ws, size_t ws_size,
                              hipStream_t stream)
{
    const float* x    = (const float*)d_in[0];
    const int*   mask = (const int*)d_in[1];
    const float* Wih  = (const float*)d_in[2];
    const float* Whh  = (const float*)d_in[3];
    const float* bih  = (const float*)d_in[4];
    const float* bhh  = (const float*)d_in[5];
    const float* Wq = (const float*)d_in[6];   const float* bq = (const float*)d_in[7];
    const float* Wk = (const float*)d_in[8];   const float* bk = (const float*)d_in[9];
    const float* Wv = (const float*)d_in[10];  const float* bv = (const float*)d_in[11];
    const float* Wo = (const float*)d_in[12];  const float* bo = (const float*)d_in[13];
    const float* W1 = (const float*)d_in[14];  const float* b1 = (const float*)d_in[15];
    const float* W2 = (const float*)d_in[16];  const float* b2 = (const float*)d_in[17];
    const float* g1 = (const float*)d_in[18];  const float* be1 = (const float*)d_in[19];
    const float* g2 = (const float*)d_in[20];  const float* be2 = (const float*)d_in[21];
    const float* Fq = (const float*)d_in[22];  const float* fbq = (const float*)d_in[23];
    const float* Fk = (const float*)d_in[24];  const float* fbk = (const float*)d_in[25];
    const float* Fv = (const float*)d_in[26];  const float* fbv = (const float*)d_in[27];
    const float* Fout = (const float*)d_in[28]; const float* fbout = (const float*)d_in[29];
    float* out = (float*)d_out;
    float* ws  = (float*)d_ws;

    float* emb = ws;   // 1048576 floats

    gru_mfma_kernel<<<dim3(DD, BB / 16), 512, 0, stream>>>(x, mask, Wih, Whh, bih, bhh, emb);
    tail_kernel<<<BB, 512, 0, stream>>>(
        emb, Wq, bq, Wk, bk, Wv, bv, Wo, bo, W1, b1, W2, b2,
        g1, be1, g2, be2, Fq, fbq, Fk, fbk, Fv, fbv, Fout, fbout, out);
}